// Round 1
// 1032.671 us; speedup vs baseline: 1.3040x; 1.3040x over previous
//
#include <hip/hip_runtime.h>
#include <hip/hip_bf16.h>
#include <math.h>

#define S 2048
#define HID 1024
#define NH 8
#define HD 128
#define INTER 4096
#define EPSV 1e-6f
#define THETA 10000.0f

typedef __hip_bfloat16 bf16;
typedef unsigned short u16;
typedef __attribute__((ext_vector_type(8))) short bf16x8;  // 8 bf16 = 4 VGPRs
typedef __attribute__((ext_vector_type(4))) float f32x4;

__device__ inline float bu2f(u16 u) {
    unsigned int x = ((unsigned int)u) << 16;
    return __uint_as_float(x);
}
__device__ inline u16 f2bu(float f) {
    bf16 h = __float2bfloat16(f);
    return *reinterpret_cast<u16*>(&h);
}
// Dual-dtype input load (raw harness inputs): isbf ? bf16 : f32
__device__ inline float ldin(const void* p, size_t i, bool isbf) {
    return isbf ? bu2f(((const u16*)p)[i]) : ((const float*)p)[i];
}
__device__ inline float gelu_tanh(float x) {
    float x3 = x * x * x;
    return 0.5f * x * (1.f + tanhf(0.7978845608028654f * (x + 0.044715f * x3)));
}

// ---------------- dtype probe (round-1 notes) ----------------
__global__ __launch_bounds__(256) void probe_kernel(const unsigned short* __restrict__ x,
                                                    int* __restrict__ flag) {
    __shared__ int red[256];
    int tid = threadIdx.x;
    int cnt = 0;
    for (int i = tid; i < 2048; i += 256) {
        unsigned short u = x[2 * i];
        int e = (u >> 7) & 0xFF;
        cnt += (e >= 110 && e <= 135) ? 1 : 0;
    }
    red[tid] = cnt;
    __syncthreads();
    for (int off = 128; off > 0; off >>= 1) {
        if (tid < off) red[tid] += red[tid + off];
        __syncthreads();
    }
    if (tid == 0) *flag = (red[0] > 1024) ? 1 : 0;
}

// ---------------- weight transpose+convert: W (KxN, input dtype) -> WT (NxK, bf16) ----------------
__global__ __launch_bounds__(256) void transpose_w(const void* __restrict__ W,
                                                   u16* __restrict__ WT,
                                                   const int* __restrict__ flag,
                                                   int K, int N) {
    bool isbf = (*flag != 0);
    __shared__ float t[32][33];
    int n0 = blockIdx.x * 32, k0 = blockIdx.y * 32;
    int c = threadIdx.x & 31, r = threadIdx.x >> 5;
#pragma unroll
    for (int p = 0; p < 4; p++)
        t[r + 8 * p][c] = ldin(W, (size_t)(k0 + r + 8 * p) * N + n0 + c, isbf);
    __syncthreads();
#pragma unroll
    for (int p = 0; p < 4; p++) {
        int row = r + 8 * p;
        WT[(size_t)(n0 + row) * K + k0 + c] = f2bu(t[c][row]);
    }
}

// ---------------- V transpose: V[key][dh] (stride sv, bf16) -> VT[dh][key] (2048 keys) ----------------
__global__ __launch_bounds__(256) void transpose_v(const u16* __restrict__ V, int sv,
                                                   u16* __restrict__ VT) {
    __shared__ u16 t[32][33];
    int k0 = blockIdx.x * 32;  // key tile
    int d0 = blockIdx.y * 32;  // dh tile
    int c = threadIdx.x & 31, r = threadIdx.x >> 5;
#pragma unroll
    for (int p = 0; p < 4; p++)
        t[r + 8 * p][c] = V[(size_t)(k0 + r + 8 * p) * sv + d0 + c];
    __syncthreads();
#pragma unroll
    for (int p = 0; p < 4; p++)
        VT[(size_t)(d0 + r + 8 * p) * S + k0 + c] = t[c][r + 8 * p];
}

// ---------------- RMSNorm -> bf16 ----------------
__global__ __launch_bounds__(256) void rmsnorm_kernel(const void* __restrict__ x,
                                                      const void* __restrict__ w,
                                                      u16* __restrict__ y,
                                                      const int* __restrict__ flag,
                                                      int dual) {
    bool isbf = (*flag != 0);
    bool xbf = dual && isbf;
    int row = blockIdx.x;
    size_t base = (size_t)row * HID;
    __shared__ float red[256];
    float xv[4];
    float s = 0.f;
#pragma unroll
    for (int i = 0; i < 4; i++) {
        float v = ldin(x, base + threadIdx.x + 256 * i, xbf);
        xv[i] = v;
        s += v * v;
    }
    red[threadIdx.x] = s;
    __syncthreads();
    for (int off = 128; off > 0; off >>= 1) {
        if (threadIdx.x < off) red[threadIdx.x] += red[threadIdx.x + off];
        __syncthreads();
    }
    float scale = rsqrtf(red[0] / (float)HID + EPSV);
#pragma unroll
    for (int i = 0; i < 4; i++) {
        int c = threadIdx.x + 256 * i;
        y[base + c] = f2bu(xv[i] * scale * (1.f + ldin(w, c, isbf)));
    }
}

// ================= MFMA GEMM (verified round 4) =================
template <int BM, int BN, int WRN, int WCN, int EPI>
__global__ __launch_bounds__(256) void gemm_mfma(const u16* __restrict__ A,
                                                 const u16* __restrict__ BT,
                                                 float* __restrict__ Cf,
                                                 u16* __restrict__ Cb,
                                                 const void* __restrict__ res,
                                                 const int* __restrict__ flag,
                                                 int M, int N, int K) {
    constexpr int BK = 32, LDK = 40;
    constexpr int WM = BM / WRN, WN = BN / WCN, TI = WM / 16, TJ = WN / 16;
    constexpr int AIT = BM / 64, BIT = BN / 64;
    __shared__ u16 As[BM * LDK];
    __shared__ u16 Bs[BN * LDK];
    int tid = threadIdx.x, lane = tid & 63, wv = tid >> 6;
    int wr = wv / WCN, wc = wv % WCN;
    int m = lane & 15, quad = lane >> 4;
    int m0 = blockIdx.y * BM, n0 = blockIdx.x * BN;
    f32x4 acc[TI][TJ] = {};
    for (int k0 = 0; k0 < K; k0 += BK) {
        __syncthreads();
#pragma unroll
        for (int i = 0; i < AIT; i++) {
            int l = tid + 256 * i;
            int row = l >> 2, kq = l & 3;
            *reinterpret_cast<uint4*>(&As[row * LDK + kq * 8]) =
                *reinterpret_cast<const uint4*>(&A[(size_t)(m0 + row) * K + k0 + kq * 8]);
        }
#pragma unroll
        for (int i = 0; i < BIT; i++) {
            int l = tid + 256 * i;
            int row = l >> 2, kq = l & 3;
            *reinterpret_cast<uint4*>(&Bs[row * LDK + kq * 8]) =
                *reinterpret_cast<const uint4*>(&BT[(size_t)(n0 + row) * K + k0 + kq * 8]);
        }
        __syncthreads();
        bf16x8 af[TI], bf_[TJ];
#pragma unroll
        for (int i = 0; i < TI; i++)
            af[i] = *reinterpret_cast<const bf16x8*>(&As[(wr * WM + i * 16 + m) * LDK + quad * 8]);
#pragma unroll
        for (int j = 0; j < TJ; j++)
            bf_[j] = *reinterpret_cast<const bf16x8*>(&Bs[(wc * WN + j * 16 + m) * LDK + quad * 8]);
#pragma unroll
        for (int i = 0; i < TI; i++)
#pragma unroll
            for (int j = 0; j < TJ; j++)
                acc[i][j] = __builtin_amdgcn_mfma_f32_16x16x32_bf16(af[i], bf_[j], acc[i][j], 0, 0, 0);
    }
    bool isbf = (EPI == 1) ? (*flag != 0) : false;
#pragma unroll
    for (int i = 0; i < TI; i++) {
#pragma unroll
        for (int j = 0; j < TJ; j++) {
#pragma unroll
            for (int r = 0; r < 4; r++) {
                int row = m0 + wr * WM + i * 16 + quad * 4 + r;
                int col = n0 + wc * WN + j * 16 + m;
                size_t idx = (size_t)row * N + col;
                float v = acc[i][j][r];
                if (EPI == 0) Cb[idx] = f2bu(v);
                else if (EPI == 1) Cf[idx] = v + ldin(res, idx, isbf);
                else Cf[idx] = Cf[idx] + v;
            }
        }
    }
}

// ------------- Fused gated MLP MFMA: C(bf16) = gelu(A@Wg) * (A@Wu) -------------
template <int BM, int BN, int WRN, int WCN>
__global__ __launch_bounds__(256) void gemm_gated_mfma(const u16* __restrict__ A,
                                                       const u16* __restrict__ BgT,
                                                       const u16* __restrict__ BuT,
                                                       u16* __restrict__ C,
                                                       int M, int N, int K) {
    constexpr int BK = 32, LDK = 40;
    constexpr int WM = BM / WRN, WN = BN / WCN, TI = WM / 16, TJ = WN / 16;
    constexpr int AIT = BM / 64, BIT = BN / 64;
    __shared__ u16 As[BM * LDK];
    __shared__ u16 Bgs[BN * LDK];
    __shared__ u16 Bus[BN * LDK];
    int tid = threadIdx.x, lane = tid & 63, wv = tid >> 6;
    int wr = wv / WCN, wc = wv % WCN;
    int m = lane & 15, quad = lane >> 4;
    int m0 = blockIdx.y * BM, n0 = blockIdx.x * BN;
    f32x4 accg[TI][TJ] = {};
    f32x4 accu[TI][TJ] = {};
    for (int k0 = 0; k0 < K; k0 += BK) {
        __syncthreads();
#pragma unroll
        for (int i = 0; i < AIT; i++) {
            int l = tid + 256 * i;
            int row = l >> 2, kq = l & 3;
            *reinterpret_cast<uint4*>(&As[row * LDK + kq * 8]) =
                *reinterpret_cast<const uint4*>(&A[(size_t)(m0 + row) * K + k0 + kq * 8]);
        }
#pragma unroll
        for (int i = 0; i < BIT; i++) {
            int l = tid + 256 * i;
            int row = l >> 2, kq = l & 3;
            *reinterpret_cast<uint4*>(&Bgs[row * LDK + kq * 8]) =
                *reinterpret_cast<const uint4*>(&BgT[(size_t)(n0 + row) * K + k0 + kq * 8]);
            *reinterpret_cast<uint4*>(&Bus[row * LDK + kq * 8]) =
                *reinterpret_cast<const uint4*>(&BuT[(size_t)(n0 + row) * K + k0 + kq * 8]);
        }
        __syncthreads();
        bf16x8 af[TI], bg[TJ], bu[TJ];
#pragma unroll
        for (int i = 0; i < TI; i++)
            af[i] = *reinterpret_cast<const bf16x8*>(&As[(wr * WM + i * 16 + m) * LDK + quad * 8]);
#pragma unroll
        for (int j = 0; j < TJ; j++) {
            bg[j] = *reinterpret_cast<const bf16x8*>(&Bgs[(wc * WN + j * 16 + m) * LDK + quad * 8]);
            bu[j] = *reinterpret_cast<const bf16x8*>(&Bus[(wc * WN + j * 16 + m) * LDK + quad * 8]);
        }
#pragma unroll
        for (int i = 0; i < TI; i++)
#pragma unroll
            for (int j = 0; j < TJ; j++) {
                accg[i][j] = __builtin_amdgcn_mfma_f32_16x16x32_bf16(af[i], bg[j], accg[i][j], 0, 0, 0);
                accu[i][j] = __builtin_amdgcn_mfma_f32_16x16x32_bf16(af[i], bu[j], accu[i][j], 0, 0, 0);
            }
    }
#pragma unroll
    for (int i = 0; i < TI; i++)
#pragma unroll
        for (int j = 0; j < TJ; j++)
#pragma unroll
            for (int r = 0; r < 4; r++) {
                int row = m0 + wr * WM + i * 16 + quad * 4 + r;
                int col = n0 + wc * WN + j * 16 + m;
                C[(size_t)row * N + col] = f2bu(gelu_tanh(accg[i][j][r]) * accu[i][j][r]);
            }
}

// ---------------- RoPE: read qkv (bf16, stride 3072), write qr/kr (bf16, stride 1024) ----------------
__global__ __launch_bounds__(64) void rope_kernel(const u16* __restrict__ qkv,
                                                  u16* __restrict__ qr,
                                                  u16* __restrict__ kr) {
    int b = blockIdx.x;
    int t = b >> 3, h = b & 7;
    int i = threadIdx.x;  // 0..63
    size_t ib = (size_t)t * 3072 + h * HD;
    size_t ob = (size_t)t * HID + h * HD;
    float inv = powf(THETA, -(float)(2 * i) / (float)HD);
    float f = (float)t * inv;
    float c = cosf(f), s = sinf(f);
    float q1 = bu2f(qkv[ib + i]), q2 = bu2f(qkv[ib + i + 64]);
    qr[ob + i] = f2bu(q1 * c - q2 * s);
    qr[ob + i + 64] = f2bu(q2 * c + q1 * s);
    float k1 = bu2f(qkv[ib + 1024 + i]), k2 = bu2f(qkv[ib + 1024 + i + 64]);
    kr[ob + i] = f2bu(k1 * c - k2 * s);
    kr[ob + i + 64] = f2bu(k2 * c + k1 * s);
}

// ============ MFMA flash attention (v2: swapped QK^T, in-register softmax) ============
// Block: 64 queries x 1 head; 4 waves, wave w owns q-rows 16w..16w+15 (q = lane&15).
// QK^T computed SWAPPED: sc = mfma(K_frag, Q_frag) -> sc[ct][r] = S^T[key][q] with
// key = 16ct + 4quad + r, q = 16w + col. Each lane holds a full 64-key P^T column for
// ONE query -> softmax is an in-register tree + 2 cross-quad shuffles (xor16/xor32);
// m/l/alpha are per-lane scalars. P is redistributed into the PV b-frag layout with
// 16 ds_bpermutes (no LDS P buffer). PV computes O^T = V^T @ P^T with the same
// fragment convention (V^T rows are the a-frag). K and V^T tiles are staged unpadded
// (64B rows) with XOR swizzle byte ^= ((row>>1)&3)<<4, which spreads the 16-row
// column reads over all 8 bank groups while keeping uint4 staging writes in-row.
// LDS: 32 KB total (was 49 KB) -> 4+ blocks/CU.
__device__ inline int swz64(int row, int b) {
    return row * 64 + (b ^ (((row >> 1) & 3) << 4));
}

template <bool CAUSAL>
__global__ __launch_bounds__(256, 4) void attn_mfma_kernel(
    const u16* __restrict__ qa, const u16* __restrict__ qb, int sq,
    const u16* __restrict__ ka, const u16* __restrict__ kb, int sk,
    const u16* __restrict__ vta, const u16* __restrict__ vtb,
    u16* __restrict__ Out, int nkeys) {
    __shared__ char Ks[4 * 64 * 64];    // [t=d/32][key 0..63][32 d], swizzled 64B rows
    __shared__ char VTs[2 * 128 * 64];  // [ks=key/32][d 0..127][32 keys], swizzled

    int tid = threadIdx.x;
    int lane = tid & 63, w = tid >> 6;
    int col = lane & 15, quad = lane >> 4;
    int q0 = blockIdx.x * 64;
    int h = blockIdx.y;
    const float scale = 0.08838834764831845f;  // 1/sqrt(128)

    // Q b-frags (4 d-steps of 32) straight from global into registers
    int q0r = CAUSAL ? q0 : (q0 & (S - 1));
    const u16* qp = ((CAUSAL || q0 < S) ? qa : qb) + (size_t)q0r * sq;
    bf16x8 aq[4];
#pragma unroll
    for (int t = 0; t < 4; t++)
        aq[t] = *reinterpret_cast<const bf16x8*>(
            qp + (size_t)(16 * w + col) * sq + h * HD + 32 * t + quad * 8);

    f32x4 o[8] = {};           // O^T: o[nt][r] = O[q][d = 16nt + 4quad + r]
    float m_ = -1e30f, l_ = 0.f;

    // bpermute source lanes for P redistribution (derivation in session notes):
    // target quad t needs pu[2ks + (t>>1)] from source quads 2(t&1) and 2(t&1)+1.
    int sA = col + 16 * (2 * (quad & 1));
    int sB = sA + 16;
    bool hi = (quad >> 1) != 0;

    int ntiles = CAUSAL ? (q0 >> 6) + 1 : (nkeys >> 6);
    for (int tt = 0; tt < ntiles; tt++) {
        int j0 = tt * 64;
        int j0r = j0 & (S - 1);
        bool eb = (!CAUSAL) && (j0 >= S);
        const u16* kp = eb ? kb : ka;
        const u16* vp = eb ? vtb : vta;
        __syncthreads();  // prev iter's compute done before restaging
        // ---- stage K tile: 64 keys x 128 d ----
#pragma unroll
        for (int i = 0; i < 4; i++) {
            int l = tid + 256 * i;
            int key = l >> 4, c = l & 15;
            int t = c >> 2, kq = c & 3;
            *reinterpret_cast<uint4*>(&Ks[t * 4096 + swz64(key, kq * 16)]) =
                *reinterpret_cast<const uint4*>(kp + (size_t)(j0r + key) * sk + h * HD + c * 8);
        }
        // ---- stage V^T tile: 128 d x 64 keys ----
#pragma unroll
        for (int i = 0; i < 4; i++) {
            int l = tid + 256 * i;
            int d = l >> 3, c = l & 7;
            int ks = c >> 2, kq = c & 3;
            *reinterpret_cast<uint4*>(&VTs[ks * 8192 + swz64(d, kq * 16)]) =
                *reinterpret_cast<const uint4*>(vp + (size_t)(h * HD + d) * S + j0r + c * 8);
        }
        __syncthreads();

        // ---- QK^T (swapped): wave computes 64k x 16q ----
        f32x4 sc[4] = {};
        __builtin_amdgcn_s_setprio(1);
#pragma unroll
        for (int t = 0; t < 4; t++) {
#pragma unroll
            for (int ct = 0; ct < 4; ct++) {
                bf16x8 kf = *reinterpret_cast<const bf16x8*>(
                    &Ks[t * 4096 + swz64(16 * ct + col, quad * 16)]);
                sc[ct] = __builtin_amdgcn_mfma_f32_16x16x32_bf16(kf, aq[t], sc[ct], 0, 0, 0);
            }
        }
        __builtin_amdgcn_s_setprio(0);
        bool diag = CAUSAL && (j0 == q0);
#pragma unroll
        for (int ct = 0; ct < 4; ct++) {
#pragma unroll
            for (int r = 0; r < 4; r++) {
                float v = sc[ct][r] * scale;
                if (diag && (16 * ct + 4 * quad + r > 16 * w + col)) v = -1e30f;
                sc[ct][r] = v;
            }
        }

        // ---- per-lane online softmax (one query per lane) ----
        float mx0 = fmaxf(fmaxf(sc[0][0], sc[0][1]), fmaxf(sc[0][2], sc[0][3]));
        float mx1 = fmaxf(fmaxf(sc[1][0], sc[1][1]), fmaxf(sc[1][2], sc[1][3]));
        float mx2 = fmaxf(fmaxf(sc[2][0], sc[2][1]), fmaxf(sc[2][2], sc[2][3]));
        float mx3 = fmaxf(fmaxf(sc[3][0], sc[3][1]), fmaxf(sc[3][2], sc[3][3]));
        float rmax = fmaxf(fmaxf(mx0, mx1), fmaxf(mx2, mx3));
        rmax = fmaxf(rmax, __shfl_xor(rmax, 16));
        rmax = fmaxf(rmax, __shfl_xor(rmax, 32));
        float mn = fmaxf(m_, rmax);
        float al = __expf(m_ - mn);
#pragma unroll
        for (int ct = 0; ct < 4; ct++)
#pragma unroll
            for (int r = 0; r < 4; r++) sc[ct][r] = __expf(sc[ct][r] - mn);
        float s0 = (sc[0][0] + sc[0][1]) + (sc[0][2] + sc[0][3]);
        float s1 = (sc[1][0] + sc[1][1]) + (sc[1][2] + sc[1][3]);
        float s2 = (sc[2][0] + sc[2][1]) + (sc[2][2] + sc[2][3]);
        float s3 = (sc[3][0] + sc[3][1]) + (sc[3][2] + sc[3][3]);
        float rs = (s0 + s1) + (s2 + s3);
        rs += __shfl_xor(rs, 16);
        rs += __shfl_xor(rs, 32);
        l_ = l_ * al + rs;
        m_ = mn;

        // ---- pack P^T to bf16 pairs: pu[ct] covers keys 16ct+4quad+{0..3} ----
        unsigned int pu[4][2];
#pragma unroll
        for (int ct = 0; ct < 4; ct++) {
            pu[ct][0] = (unsigned int)f2bu(sc[ct][0]) | ((unsigned int)f2bu(sc[ct][1]) << 16);
            pu[ct][1] = (unsigned int)f2bu(sc[ct][2]) | ((unsigned int)f2bu(sc[ct][3]) << 16);
        }

        // ---- O^T rescale ----
#pragma unroll
        for (int nt = 0; nt < 8; nt++)
#pragma unroll
            for (int r = 0; r < 4; r++) o[nt][r] *= al;

        // ---- PV: O^T += V^T @ P^T; b-frag gathered via bpermute ----
#pragma unroll
        for (int ks = 0; ks < 2; ks++) {
            unsigned int a0 = __shfl(pu[2 * ks][0], sA);
            unsigned int a1 = __shfl(pu[2 * ks][1], sA);
            unsigned int c0 = __shfl(pu[2 * ks + 1][0], sA);
            unsigned int c1 = __shfl(pu[2 * ks + 1][1], sA);
            unsigned int b0 = __shfl(pu[2 * ks][0], sB);
            unsigned int b1 = __shfl(pu[2 * ks][1], sB);
            unsigned int g0 = __shfl(pu[2 * ks + 1][0], sB);
            unsigned int g1 = __shfl(pu[2 * ks + 1][1], sB);
            union {
                unsigned int u[4];
                bf16x8 v;
            } pb;
            pb.u[0] = hi ? c0 : a0;
            pb.u[1] = hi ? c1 : a1;
            pb.u[2] = hi ? g0 : b0;
            pb.u[3] = hi ? g1 : b1;
            __builtin_amdgcn_s_setprio(1);
#pragma unroll
            for (int nt = 0; nt < 8; nt++) {
                bf16x8 vf = *reinterpret_cast<const bf16x8*>(
                    &VTs[ks * 8192 + swz64(16 * nt + col, quad * 16)]);
                o[nt] = __builtin_amdgcn_mfma_f32_16x16x32_bf16(vf, pb.v, o[nt], 0, 0, 0);
            }
            __builtin_amdgcn_s_setprio(0);
        }
    }

    // ---- epilogue: O /= l, write bf16 (stride HID); r-values are contiguous in d ----
    float inv = 1.f / l_;
    size_t rowoff = (size_t)(q0 + 16 * w + col) * HID + (size_t)h * HD + 4 * quad;
#pragma unroll
    for (int nt = 0; nt < 8; nt++) {
        ushort4 st;
        st.x = f2bu(o[nt][0] * inv);
        st.y = f2bu(o[nt][1] * inv);
        st.z = f2bu(o[nt][2] * inv);
        st.w = f2bu(o[nt][3] * inv);
        *reinterpret_cast<ushort4*>(&Out[rowoff + 16 * nt]) = st;
    }
}

// ---------------- f32 -> output dtype (per flag) ----------------
__global__ __launch_bounds__(256) void store_out_kernel(const float* __restrict__ a,
                                                        const float* __restrict__ b,
                                                        void* __restrict__ out,
                                                        const int* __restrict__ flag) {
    bool isbf = (*flag != 0);
    size_t i = (size_t)blockIdx.x * 256 + threadIdx.x;
    const size_t MM = (size_t)S * HID;
    float v = (i < MM) ? a[i] : b[i - MM];
    if (isbf)
        ((bf16*)out)[i] = __float2bfloat16(v);
    else
        ((float*)out)[i] = v;
}

extern "C" void kernel_launch(void* const* d_in, const int* in_sizes, int n_in,
                              void* d_out, int out_size, void* d_ws, size_t ws_size,
                              hipStream_t stream) {
    const void* x[2] = {d_in[0], d_in[1]};
    const void* w_ln[2] = {d_in[5], d_in[14]};
    const void* w_q[2] = {d_in[6], d_in[15]};
    const void* w_k[2] = {d_in[7], d_in[16]};
    const void* w_v[2] = {d_in[8], d_in[17]};
    const void* w_o[2] = {d_in[9], d_in[18]};
    const void* w_pln[2] = {d_in[10], d_in[19]};
    const void* w_g[2] = {d_in[11], d_in[20]};
    const void* w_u[2] = {d_in[12], d_in[21]};
    const void* w_d[2] = {d_in[13], d_in[22]};

    char* base = (char*)d_ws;
    int* flag = (int*)base;
    u16* p = (u16*)(base + 256);
    const size_t E_QKV = (size_t)S * 3072;
    const size_t E_SH = (size_t)S * HID;
    const size_t E_GT = (size_t)S * INTER;
    const size_t E_VT = (size_t)NH * HD * S;  // 2.1M u16 per expert

    u16* qkv[2] = {p, p + E_QKV};            p += 2 * E_QKV;
    u16* qr = p;                             p += E_SH;
    u16* kr = p;                             p += E_SH;
    u16* h_bf = p;                           p += E_SH;
    u16* attnbuf = p;                        p += E_SH;
    u16* vtg[2] = {p, p + E_VT};             p += 2 * E_VT;
    u16* gated = p;                          p += E_GT;  // mixed overlays gated
    u16* mixed = gated;
    u16* wqkvT = p;                          p += (size_t)3072 * 1024;
    u16* woT[2] = {p, p + (size_t)1024 * 1024};  p += 2 * (size_t)1024 * 1024;
    u16* wgT = p;                            p += (size_t)INTER * 1024;
    u16* wuT = p;                            p += (size_t)INTER * 1024;
    u16* wdT = p;                            p += (size_t)1024 * INTER;
    float* fbase = (float*)(((size_t)p + 255) & ~(size_t)255);
    float* outX[2] = {fbase, fbase + E_SH};

    probe_kernel<<<1, 256, 0, stream>>>((const unsigned short*)d_in[0], flag);

    for (int e = 0; e < 2; e++) {
        transpose_w<<<dim3(1024 / 32, 1024 / 32), 256, 0, stream>>>(w_q[e], wqkvT, flag, 1024, 1024);
        transpose_w<<<dim3(1024 / 32, 1024 / 32), 256, 0, stream>>>(w_k[e], wqkvT + (size_t)1024 * 1024, flag, 1024, 1024);
        transpose_w<<<dim3(1024 / 32, 1024 / 32), 256, 0, stream>>>(w_v[e], wqkvT + (size_t)2048 * 1024, flag, 1024, 1024);
        transpose_w<<<dim3(1024 / 32, 1024 / 32), 256, 0, stream>>>(w_o[e], woT[e], flag, 1024, 1024);
        transpose_w<<<dim3(INTER / 32, 1024 / 32), 256, 0, stream>>>(w_g[e], wgT, flag, 1024, INTER);
        transpose_w<<<dim3(INTER / 32, 1024 / 32), 256, 0, stream>>>(w_u[e], wuT, flag, 1024, INTER);
        transpose_w<<<dim3(1024 / 32, INTER / 32), 256, 0, stream>>>(w_d[e], wdT, flag, INTER, 1024);

        rmsnorm_kernel<<<S, 256, 0, stream>>>(x[e], w_ln[e], h_bf, flag, 1);
        gemm_mfma<128, 128, 2, 2, 0><<<dim3(3072 / 128, S / 128), 256, 0, stream>>>(
            h_bf, wqkvT, nullptr, qkv[e], nullptr, flag, S, 3072, 1024);
        rope_kernel<<<S * NH, 64, 0, stream>>>(qkv[e], qr, kr);
        transpose_v<<<dim3(S / 32, 1024 / 32), 256, 0, stream>>>(qkv[e] + 2048, 3072, vtg[e]);
        attn_mfma_kernel<true><<<dim3(S / 64, NH), 256, 0, stream>>>(
            qr, qr, HID, kr, kr, HID, vtg[e], vtg[e], attnbuf, S);
        gemm_mfma<64, 128, 1, 4, 1><<<dim3(1024 / 128, S / 64), 256, 0, stream>>>(
            attnbuf, woT[e], outX[e], nullptr, x[e], flag, S, 1024, 1024);
        rmsnorm_kernel<<<S, 256, 0, stream>>>(outX[e], w_pln[e], h_bf, flag, 0);
        gemm_gated_mfma<128, 64, 2, 2><<<dim3(INTER / 64, S / 128), 256, 0, stream>>>(
            h_bf, wgT, wuT, gated, S, INTER, 1024);
        gemm_mfma<64, 128, 1, 4, 2><<<dim3(1024 / 128, S / 64), 256, 0, stream>>>(
            gated, wdT, outX[e], nullptr, nullptr, flag, S, 1024, INTER);
    }

    attn_mfma_kernel<false><<<dim3(2 * S / 64, NH), 256, 0, stream>>>(
        qkv[0], qkv[1], 3072, qkv[0] + 1024, qkv[1] + 1024, 3072,
        vtg[0], vtg[1], mixed, 2 * S);
    gemm_mfma<64, 128, 1, 4, 2><<<dim3(1024 / 128, S / 64), 256, 0, stream>>>(
        mixed, woT[0], outX[0], nullptr, nullptr, flag, S, 1024, 1024);
    gemm_mfma<64, 128, 1, 4, 2><<<dim3(1024 / 128, S / 64), 256, 0, stream>>>(
        mixed + E_SH, woT[1], outX[1], nullptr, nullptr, flag, S, 1024, 1024);

    store_out_kernel<<<(2 * E_SH) / 256, 256, 0, stream>>>(outX[0], outX[1], d_out, flag);
}